// Round 4
// baseline (350.867 us; speedup 1.0000x reference)
//
#include <hip/hip_runtime.h>

#define NROW 8192
#define NCOL 8192
#define RANK 256

#define BM 128
#define BN 128

typedef __bf16  bf16x8 __attribute__((ext_vector_type(8)));
typedef float   f32x4  __attribute__((ext_vector_type(4)));

__device__ __forceinline__ unsigned short f2bf(float f) {
    // round-to-nearest-even fp32 -> bf16
    unsigned int u = __builtin_bit_cast(unsigned int, f);
    u += 0x7fffu + ((u >> 16) & 1u);
    return (unsigned short)(u >> 16);
}

// --- Prologue A: X (fp32, NROW x RANK) -> Xb (bf16) + x2 row norms ---
__global__ __launch_bounds__(256) void prep_x(const float* __restrict__ X,
                                              unsigned short* __restrict__ Xb,
                                              float* __restrict__ x2) {
    const int row  = blockIdx.x * 4 + (threadIdx.x >> 6);
    const int lane = threadIdx.x & 63;
    const float4 v = ((const float4*)(X + (size_t)row * RANK))[lane];
    float s = v.x * v.x + v.y * v.y + v.z * v.z + v.w * v.w;
    ushort4 b;
    b.x = f2bf(v.x); b.y = f2bf(v.y); b.z = f2bf(v.z); b.w = f2bf(v.w);
    ((ushort4*)(Xb + (size_t)row * RANK))[lane] = b;
    #pragma unroll
    for (int off = 32; off > 0; off >>= 1) s += __shfl_down(s, off);
    if (lane == 0) x2[row] = s;
}

// --- Prologue B: Y (fp32, RANK x NCOL) -> Ybt (bf16, NCOL x RANK) + y2 ---
__global__ __launch_bounds__(256) void prep_y(const float* __restrict__ Y,
                                              unsigned short* __restrict__ Ybt,
                                              float* __restrict__ y2) {
    __shared__ float tile[64][65];   // +1 pad: conflict-free transposed reads
    __shared__ float part[256];
    const int t  = threadIdx.x;
    const int j0 = blockIdx.x * 64;
    const int tq = t >> 6;           // 0..3
    const int tl = t & 63;
    float acc = 0.f;
    for (int c = 0; c < 4; ++c) {    // k chunks of 64
        const int k0 = c * 64;
        #pragma unroll
        for (int i = 0; i < 16; ++i) {
            const int kk = tq * 16 + i;
            const float v = Y[(size_t)(k0 + kk) * NCOL + j0 + tl]; // coalesced
            tile[kk][tl] = v;
            acc += v * v;            // column j0+tl partial
        }
        __syncthreads();
        #pragma unroll
        for (int i = 0; i < 16; ++i) {
            const int jj = tq * 16 + i;
            Ybt[(size_t)(j0 + jj) * RANK + k0 + tl] = f2bf(tile[tl][jj]); // coalesced
        }
        __syncthreads();
    }
    part[t] = acc;
    __syncthreads();
    if (t < 64)
        y2[j0 + t] = part[t] + part[t + 64] + part[t + 128] + part[t + 192];
}

// --- Main: bf16 MFMA GEMM + fused L2 epilogue ---
// K=256 is tiny: stage ONLY B (full-K, 64 KB LDS, XOR-swizzled), read A
// fragments direct from global (everything is L2-resident, 8 MB total).
// ONE barrier per block, zero in-loop vmcnt drains, no double buffer.
// 64 KB LDS -> 2 blocks/CU: co-resident block's MFMAs cover staging latency.
//
// B LDS swizzle (rule: both-sides-or-neither with global_load_lds):
//   row = 512 B = 32 slots of 16 B. Stored slot s' = s ^ (row&7), achieved by
//   pre-swizzling the per-lane GLOBAL source slot; read applies the same XOR.
//   Fragment read: lanes 0-15 hit 8 distinct 4-bank groups -> conflict-free.
//
// Operand-SWAPPED mfma: acc[mt][nt] element r at lane L holds
//   C[row = rowBase+waveM+mt*16+(L&15)][col = colBase+waveN+nt*16+(L>>4)*4+r]
__global__ __launch_bounds__(256, 2)
void l2_gemm(const unsigned short* __restrict__ A,   // Xb  [NROW][RANK]
             const unsigned short* __restrict__ Bt,  // Ybt [NCOL][RANK]
             const float* __restrict__ x2,
             const float* __restrict__ y2,
             const float* __restrict__ beta_p,
             float* __restrict__ out) {
    __shared__ alignas(16) unsigned short Bs[BN * RANK];   // 64 KB, full-K

    const int t    = threadIdx.x;
    const int wid  = t >> 6;
    const int lane = t & 63;

    // XCD-aware swizzle (4096 blocks, 8 XCDs, bijective): each XCD gets an
    // 8-col-tile slab; A row-panel (64 KB) reused by 8 blocks, B slab (512 KB)
    // L2-resident across the rt sweep.
    const int bid  = blockIdx.x;
    const int xcd  = bid & 7;
    const int seq  = bid >> 3;              // 0..511
    const int ct   = xcd * 8 + (seq & 7);   // col-tile
    const int rt   = seq >> 3;              // row-tile
    const int rowBase = rt * BM;
    const int colBase = ct * BN;

    const int waveM = (wid >> 1) * 64;
    const int waveN = (wid & 1) * 64;

    f32x4 acc[4][4] = {};

    // ---- stage B full-K into LDS with pre-swizzled global source ----
    // per wave: 32 rows; per instr: 64 lanes x 16 B = 2 rows (512 B each)
    {
        const int l5 = lane >> 5;            // 0..1 : row parity within pair
        const int ls = lane & 31;            // 16B slot 0..31 within row
        #pragma unroll
        for (int r = 0; r < 16; ++r) {
            const int ro = wid * 32 + r * 2 + l5;        // row in B tile
            const int cs = ls ^ (ro & 7);                // pre-swizzled slot
            const unsigned short* gp =
                Bt + (size_t)(colBase + ro) * RANK + cs * 8;
            unsigned short* lp = &Bs[(wid * 32 + r * 2) * RANK]; // wave-uniform
            __builtin_amdgcn_global_load_lds(
                (__attribute__((address_space(1))) void*)gp,
                (__attribute__((address_space(3))) void*)lp, 16, 0, 0);
        }
    }

    // ---- while B stages: prefetch kg=0 A-fragments + epilogue operands ----
    const int r0 = rowBase + waveM + (lane & 15);
    const int c0 = colBase + waveN + ((lane >> 4) << 2);
    const int koff = (lane >> 4) * 8;        // element offset within kgroup

    bf16x8 af0[4];
    #pragma unroll
    for (int mt = 0; mt < 4; ++mt)
        af0[mt] = *(const bf16x8*)(A + (size_t)(r0 + mt * 16) * RANK + koff);

    const float beta = *beta_p;
    float xv[4];
    f32x4 y4[4];
    #pragma unroll
    for (int mt = 0; mt < 4; ++mt) xv[mt] = x2[r0 + mt * 16];
    #pragma unroll
    for (int nt = 0; nt < 4; ++nt) y4[nt] = *(const f32x4*)(y2 + c0 + nt * 16);

    __syncthreads();   // the ONLY barrier: B tile ready

    // ---- K loop: 8 kgroups of 32; A direct-from-global, B from swizzled LDS
    #pragma unroll
    for (int kg = 0; kg < 8; ++kg) {
        bf16x8 af[4], bfr[4];
        if (kg == 0) {
            #pragma unroll
            for (int mt = 0; mt < 4; ++mt) af[mt] = af0[mt];
        } else {
            const int ko = kg * 32 + koff;
            #pragma unroll
            for (int mt = 0; mt < 4; ++mt)
                af[mt] = *(const bf16x8*)(A + (size_t)(r0 + mt * 16) * RANK + ko);
        }
        const int sbase = kg * 4 + (lane >> 4);          // 16B slot pre-XOR
        #pragma unroll
        for (int nt = 0; nt < 4; ++nt) {
            const int rr = waveN + nt * 16 + (lane & 15);
            const int s  = sbase ^ (rr & 7);             // swizzled read
            bfr[nt] = *(const bf16x8*)(&Bs[rr * RANK + s * 8]);
        }
        #pragma unroll
        for (int mt = 0; mt < 4; ++mt)
            #pragma unroll
            for (int nt = 0; nt < 4; ++nt)
                // SWAPPED operands: output mapping transposed (see header)
                acc[mt][nt] = __builtin_amdgcn_mfma_f32_16x16x32_bf16(
                    bfr[nt], af[mt], acc[mt][nt], 0, 0, 0);
    }

    // ---- fused epilogue: float4 non-temporal stores ----
    #pragma unroll
    for (int mt = 0; mt < 4; ++mt) {
        const int row = r0 + mt * 16;
        float* op = out + (size_t)row * NCOL + c0;
        #pragma unroll
        for (int nt = 0; nt < 4; ++nt) {
            const f32x4 a = acc[mt][nt];
            f32x4 z;
            #pragma unroll
            for (int r = 0; r < 4; ++r) {
                float d2 = xv[mt] + y4[nt][r] - 2.0f * a[r];
                z[r] = beta - __builtin_amdgcn_sqrtf(fmaxf(d2, 0.0f));
            }
            // non-temporal: keep the 268 MB output stream out of L2
            __builtin_nontemporal_store(z, (f32x4*)(op + nt * 16));
        }
    }
}

extern "C" void kernel_launch(void* const* d_in, const int* in_sizes, int n_in,
                              void* d_out, int out_size, void* d_ws, size_t ws_size,
                              hipStream_t stream) {
    const float* X    = (const float*)d_in[0];   // 8192 x 256
    const float* Y    = (const float*)d_in[1];   // 256 x 8192
    const float* beta = (const float*)d_in[2];   // scalar
    float* out = (float*)d_out;

    // workspace layout
    char* ws = (char*)d_ws;
    unsigned short* Xb  = (unsigned short*)(ws);                           // 4 MB
    unsigned short* Ybt = (unsigned short*)(ws + (size_t)4 * 1024 * 1024); // 4 MB
    float* x2 = (float*)(ws + (size_t)8 * 1024 * 1024);                    // 32 KB
    float* y2 = (float*)(ws + (size_t)8 * 1024 * 1024 + 32 * 1024);        // 32 KB

    prep_x<<<NROW / 4, 256, 0, stream>>>(X, Xb, x2);
    prep_y<<<NCOL / 64, 256, 0, stream>>>(Y, Ybt, y2);

    l2_gemm<<<dim3(4096), 256, 0, stream>>>(Xb, Ybt, x2, y2, beta, out);
}

// Round 5
// 341.649 us; speedup vs baseline: 1.0270x; 1.0270x over previous
//
#include <hip/hip_runtime.h>

#define NROW 8192
#define NCOL 8192
#define RANK 256

#define BM 128      // row-tile per iteration
#define BN 128      // col-slab per block (full-K resident in LDS)
#define NRT 8       // row-tiles per block (8 * 128 = 1024 rows per row-group)

typedef __bf16  bf16x8 __attribute__((ext_vector_type(8)));
typedef float   f32x4  __attribute__((ext_vector_type(4)));

__device__ __forceinline__ unsigned short f2bf(float f) {
    // round-to-nearest-even fp32 -> bf16
    unsigned int u = __builtin_bit_cast(unsigned int, f);
    u += 0x7fffu + ((u >> 16) & 1u);
    return (unsigned short)(u >> 16);
}

// --- Prologue A: X (fp32, NROW x RANK) -> Xb (bf16) + x2 row norms ---
__global__ __launch_bounds__(256) void prep_x(const float* __restrict__ X,
                                              unsigned short* __restrict__ Xb,
                                              float* __restrict__ x2) {
    const int row  = blockIdx.x * 4 + (threadIdx.x >> 6);
    const int lane = threadIdx.x & 63;
    const float4 v = ((const float4*)(X + (size_t)row * RANK))[lane];
    float s = v.x * v.x + v.y * v.y + v.z * v.z + v.w * v.w;
    ushort4 b;
    b.x = f2bf(v.x); b.y = f2bf(v.y); b.z = f2bf(v.z); b.w = f2bf(v.w);
    ((ushort4*)(Xb + (size_t)row * RANK))[lane] = b;
    #pragma unroll
    for (int off = 32; off > 0; off >>= 1) s += __shfl_down(s, off);
    if (lane == 0) x2[row] = s;
}

// --- Prologue B: Y (fp32, RANK x NCOL) -> Ybt (bf16, NCOL x RANK) + y2 ---
__global__ __launch_bounds__(256) void prep_y(const float* __restrict__ Y,
                                              unsigned short* __restrict__ Ybt,
                                              float* __restrict__ y2) {
    __shared__ float tile[64][65];   // +1 pad: conflict-free transposed reads
    __shared__ float part[256];
    const int t  = threadIdx.x;
    const int j0 = blockIdx.x * 64;
    const int tq = t >> 6;           // 0..3
    const int tl = t & 63;
    float acc = 0.f;
    for (int c = 0; c < 4; ++c) {    // k chunks of 64
        const int k0 = c * 64;
        #pragma unroll
        for (int i = 0; i < 16; ++i) {
            const int kk = tq * 16 + i;
            const float v = Y[(size_t)(k0 + kk) * NCOL + j0 + tl]; // coalesced
            tile[kk][tl] = v;
            acc += v * v;            // column j0+tl partial
        }
        __syncthreads();
        #pragma unroll
        for (int i = 0; i < 16; ++i) {
            const int jj = tq * 16 + i;
            Ybt[(size_t)(j0 + jj) * RANK + k0 + tl] = f2bf(tile[tl][jj]); // coalesced
        }
        __syncthreads();
    }
    part[t] = acc;
    __syncthreads();
    if (t < 64)
        y2[j0 + t] = part[t] + part[t + 64] + part[t + 128] + part[t + 192];
}

// --- Main: persistent col-slab GEMM + fused L2 epilogue ---
// K=256 is tiny -> stage B ONCE (128 cols x 256 K bf16 = 64 KB LDS,
// XOR-swizzled), ONE barrier, then sweep 8 row-tiles with ZERO further
// barriers. Stores are fire-and-forget, so iteration t+1's A-loads issue
// right behind iteration t's stores -> the loop is paced only by the HBM
// write drain (268 MB / 6.3 TB/s = 43 us chip-wide). This removes the
// m233-measured 2-phase stage/vmcnt/barrier overhead entirely, and unlike
// R4, A-loads always have prior-iteration work to hide under.
//
// Grid 512 = 64 col-slabs x 8 row-groups; b&7 = row-group = XCD (round-robin)
// so each XCD's L2 re-serves one 512 KB A-panel to all 64 of its blocks.
// 64 KB LDS -> 2 blocks/CU; co-resident blocks cover each other's bubbles.
//
// B LDS swizzle (both-sides, R4-verified): row = 32 slots of 16 B; physical
// slot p of row holds global slot p ^ (row&7) via pre-swizzled global source;
// read of logical slot s uses s ^ (row&7). Fragment reads -> 8 slot-columns
// x 2 lanes = 2-way = free.
//
// Operand-SWAPPED mfma: acc[mt][nt] elem r at lane L holds
//   C[row = rowBase+waveM+mt*16+(L&15)][col = colBase+waveN+nt*16+(L>>4)*4+r]
__global__ __launch_bounds__(256, 2)
void l2_gemm(const unsigned short* __restrict__ A,   // Xb  [NROW][RANK]
             const unsigned short* __restrict__ Bt,  // Ybt [NCOL][RANK]
             const float* __restrict__ x2,
             const float* __restrict__ y2,
             const float* __restrict__ beta_p,
             float* __restrict__ out) {
    __shared__ alignas(16) unsigned short Bs[BN * RANK];   // 64 KB, full-K

    const int t    = threadIdx.x;
    const int wid  = t >> 6;        // 0..3
    const int lane = t & 63;

    const int b   = blockIdx.x;     // 0..511
    const int cs  = b >> 3;         // col-slab 0..63
    const int rg  = b & 7;          // row-group 0..7 (== XCD under %8 round-robin)
    const int colBase    = cs * BN;
    const int rowGrpBase = rg * (NRT * BM);   // rg * 1024

    // ---- stage B slab once: 128 rows x 256 K, pre-swizzled global source ----
    {
        const int l5 = lane >> 5;            // row parity within pair
        const int ls = lane & 31;            // 16B slot 0..31 within 512B row
        #pragma unroll
        for (int r = 0; r < 16; ++r) {
            const int ro = wid * 32 + r * 2 + l5;        // row in B slab
            const int cslot = ls ^ (ro & 7);             // pre-swizzled slot
            const unsigned short* gp =
                Bt + (size_t)(colBase + ro) * RANK + cslot * 8;
            unsigned short* lp = &Bs[(wid * 32 + r * 2) * RANK]; // wave-uniform
            __builtin_amdgcn_global_load_lds(
                (__attribute__((address_space(1))) void*)gp,
                (__attribute__((address_space(3))) void*)lp, 16, 0, 0);
        }
    }

    const int waveM = (wid & 1) * 64;        // rows within 128-row tile
    const int waveN = (wid >> 1) * 64;       // cols within 128-col slab
    const int koff  = (lane >> 4) * 8;       // k-element offset of quarter-wave
    const int c0    = colBase + waveN + ((lane >> 4) << 2);

    // per-block constants while B stages
    const float beta = *beta_p;
    f32x4 y4[4];
    #pragma unroll
    for (int nt = 0; nt < 4; ++nt) y4[nt] = *(const f32x4*)(y2 + c0 + nt * 16);

    __syncthreads();   // the ONLY barrier: B slab ready

    // ---- persistent row-tile sweep: no barriers, stores fire-and-forget ----
    #pragma unroll 1
    for (int rt = 0; rt < NRT; ++rt) {
        const int rowBase = rowGrpBase + rt * BM;
        const int r0 = rowBase + waveM + (lane & 15);

        // x2 prefetch for this tile (L2-hot; latency hides under kg loop)
        float xv[4];
        #pragma unroll
        for (int mt = 0; mt < 4; ++mt) xv[mt] = x2[r0 + mt * 16];

        f32x4 acc[4][4] = {};
        #pragma unroll
        for (int kg = 0; kg < 8; ++kg) {
            bf16x8 af[4], bfr[4];
            const int ko = kg * 32 + koff;
            #pragma unroll
            for (int mt = 0; mt < 4; ++mt)
                af[mt] = *(const bf16x8*)(A + (size_t)(r0 + mt * 16) * RANK + ko);
            const int sbase = kg * 4 + (lane >> 4);      // logical 16B slot
            #pragma unroll
            for (int nt = 0; nt < 4; ++nt) {
                const int rr = waveN + nt * 16 + (lane & 15);
                const int s  = sbase ^ (rr & 7);         // swizzled read
                bfr[nt] = *(const bf16x8*)(&Bs[rr * RANK + s * 8]);
            }
            #pragma unroll
            for (int mt = 0; mt < 4; ++mt)
                #pragma unroll
                for (int nt = 0; nt < 4; ++nt)
                    // SWAPPED operands: output mapping transposed (see header)
                    acc[mt][nt] = __builtin_amdgcn_mfma_f32_16x16x32_bf16(
                        bfr[nt], af[mt], acc[mt][nt], 0, 0, 0);
        }

        // fused epilogue: float4 non-temporal stores (keep output stream
        // from evicting the L2-resident A panels / Ybt)
        #pragma unroll
        for (int mt = 0; mt < 4; ++mt) {
            const int row = r0 + mt * 16;
            float* op = out + (size_t)row * NCOL + c0;
            #pragma unroll
            for (int nt = 0; nt < 4; ++nt) {
                const f32x4 a = acc[mt][nt];
                f32x4 z;
                #pragma unroll
                for (int r = 0; r < 4; ++r) {
                    float d2 = xv[mt] + y4[nt][r] - 2.0f * a[r];
                    z[r] = beta - __builtin_amdgcn_sqrtf(fmaxf(d2, 0.0f));
                }
                __builtin_nontemporal_store(z, (f32x4*)(op + nt * 16));
            }
        }
    }
}

extern "C" void kernel_launch(void* const* d_in, const int* in_sizes, int n_in,
                              void* d_out, int out_size, void* d_ws, size_t ws_size,
                              hipStream_t stream) {
    const float* X    = (const float*)d_in[0];   // 8192 x 256
    const float* Y    = (const float*)d_in[1];   // 256 x 8192
    const float* beta = (const float*)d_in[2];   // scalar
    float* out = (float*)d_out;

    // workspace layout
    char* ws = (char*)d_ws;
    unsigned short* Xb  = (unsigned short*)(ws);                           // 4 MB
    unsigned short* Ybt = (unsigned short*)(ws + (size_t)4 * 1024 * 1024); // 4 MB
    float* x2 = (float*)(ws + (size_t)8 * 1024 * 1024);                    // 32 KB
    float* y2 = (float*)(ws + (size_t)8 * 1024 * 1024 + 32 * 1024);        // 32 KB

    prep_x<<<NROW / 4, 256, 0, stream>>>(X, Xb, x2);
    prep_y<<<NCOL / 64, 256, 0, stream>>>(Y, Ybt, y2);

    l2_gemm<<<dim3(512), 256, 0, stream>>>(Xb, Ybt, x2, y2, beta, out);
}

// Round 6
// 308.220 us; speedup vs baseline: 1.1384x; 1.1085x over previous
//
#include <hip/hip_runtime.h>

#define NROW 8192
#define NCOL 8192
#define RANK 256

#define BM 128
#define BN 128
#define BK 64
#define NKT (RANK / BK)   // 4 K-steps

typedef __bf16  bf16x8 __attribute__((ext_vector_type(8)));
typedef float   f32x4  __attribute__((ext_vector_type(4)));

__device__ __forceinline__ unsigned short f2bf(float f) {
    // round-to-nearest-even fp32 -> bf16
    unsigned int u = __builtin_bit_cast(unsigned int, f);
    u += 0x7fffu + ((u >> 16) & 1u);
    return (unsigned short)(u >> 16);
}

// --- Prologue A: X (fp32, NROW x RANK) -> Xb (bf16) + x2 row norms ---
__global__ __launch_bounds__(256) void prep_x(const float* __restrict__ X,
                                              unsigned short* __restrict__ Xb,
                                              float* __restrict__ x2) {
    const int row  = blockIdx.x * 4 + (threadIdx.x >> 6);
    const int lane = threadIdx.x & 63;
    const float4 v = ((const float4*)(X + (size_t)row * RANK))[lane];
    float s = v.x * v.x + v.y * v.y + v.z * v.z + v.w * v.w;
    ushort4 b;
    b.x = f2bf(v.x); b.y = f2bf(v.y); b.z = f2bf(v.z); b.w = f2bf(v.w);
    ((ushort4*)(Xb + (size_t)row * RANK))[lane] = b;
    #pragma unroll
    for (int off = 32; off > 0; off >>= 1) s += __shfl_down(s, off);
    if (lane == 0) x2[row] = s;
}

// --- Prologue B: Y (fp32, RANK x NCOL) -> Ybt (bf16, NCOL x RANK) + y2 ---
__global__ __launch_bounds__(256) void prep_y(const float* __restrict__ Y,
                                              unsigned short* __restrict__ Ybt,
                                              float* __restrict__ y2) {
    __shared__ float tile[64][65];   // +1 pad: conflict-free transposed reads
    __shared__ float part[256];
    const int t  = threadIdx.x;
    const int j0 = blockIdx.x * 64;
    const int tq = t >> 6;           // 0..3
    const int tl = t & 63;
    float acc = 0.f;
    for (int c = 0; c < 4; ++c) {    // k chunks of 64
        const int k0 = c * 64;
        #pragma unroll
        for (int i = 0; i < 16; ++i) {
            const int kk = tq * 16 + i;
            const float v = Y[(size_t)(k0 + kk) * NCOL + j0 + tl]; // coalesced
            tile[kk][tl] = v;
            acc += v * v;            // column j0+tl partial
        }
        __syncthreads();
        #pragma unroll
        for (int i = 0; i < 16; ++i) {
            const int jj = tq * 16 + i;
            Ybt[(size_t)(j0 + jj) * RANK + k0 + tl] = f2bf(tile[tl][jj]); // coalesced
        }
        __syncthreads();
    }
    part[t] = acc;
    __syncthreads();
    if (t < 64)
        y2[j0 + t] = part[t] + part[t + 64] + part[t + 128] + part[t + 192];
}

// --- Main: bf16 MFMA GEMM (R1 structure) + FULL-LINE store epilogue ---
// K-loop is R1's verified-best 2-phase double-buffered pipeline, untouched.
// NEW: store shape. Old epilogue: each wave-instruction scattered 16 rows x
// 64 B runs (row stride 32 KB) -> ~1.9 TB/s effective write. The harness fill
// hits 6.4 TB/s with LINEAR full-line writes. Fix: round-trip the 128x128
// fp32 output tile through the (now free) 64 KB staging LDS, then stream it
// out 2 rows x 512 B contiguous per instruction = full 128 B lines, the same
// shape as the fill.
// LDS swizzle (both phases <=2-way): 16B slot s of row r stored at s^(r&7).
//
// Operand-SWAPPED mfma: acc[mt][nt] elem r at lane L holds
//   C[row = rowBase+waveM+mt*16+(L&15)][col = colBase+waveN+nt*16+(L>>4)*4+r]
__global__ __launch_bounds__(256, 2)
void l2_gemm(const unsigned short* __restrict__ A,   // Xb  [NROW][RANK]
             const unsigned short* __restrict__ Bt,  // Ybt [NCOL][RANK]
             const float* __restrict__ x2,
             const float* __restrict__ y2,
             const float* __restrict__ beta_p,
             float* __restrict__ out) {
    // 64 KB union: staging buffers during K-loop, fp32 C-tile in epilogue
    __shared__ alignas(16) unsigned char smem[64 * 1024];
    auto As = (unsigned short (*)[BM * BK])(smem);            // [2][8192], 32 KB
    auto Bs = (unsigned short (*)[BN * BK])(smem + 32768);    // [2][8192], 32 KB
    float* Cs = (float*)smem;                                 // [128][128], 64 KB

    const int t    = threadIdx.x;
    const int wid  = t >> 6;
    const int lane = t & 63;
    const int rowBase = blockIdx.x * BM;
    const int colBase = blockIdx.y * BN;

    const int waveM = (wid >> 1) * 64;
    const int waveN = (wid & 1) * 64;

    f32x4 acc[4][4] = {};

    const int lrow = lane >> 3;        // 0..7 : row within 8-row staging chunk
    const int lcol = (lane & 7) * 8;   // 0..56: k offset (8 bf16 = 16 B)

    const unsigned short* gA = A  + (size_t)(rowBase + wid * 8 + lrow) * RANK + lcol;
    const unsigned short* gB = Bt + (size_t)(colBase + wid * 8 + lrow) * RANK + lcol;

    auto stage = [&](int buf, int kt) {
        #pragma unroll
        for (int r = 0; r < 4; ++r) {
            const int rrel = r * 32 + wid * 8;   // wave-uniform LDS row base
            __builtin_amdgcn_global_load_lds(
                (__attribute__((address_space(1))) void*)(gA + (size_t)r * 32 * RANK + kt),
                (__attribute__((address_space(3))) void*)(&As[buf][rrel * BK]), 16, 0, 0);
            __builtin_amdgcn_global_load_lds(
                (__attribute__((address_space(1))) void*)(gB + (size_t)r * 32 * RANK + kt),
                (__attribute__((address_space(3))) void*)(&Bs[buf][rrel * BK]), 16, 0, 0);
        }
    };

    auto compute = [&](int buf) {
        #pragma unroll
        for (int ks = 0; ks < BK; ks += 32) {
            const int kfrag = ks + (lane >> 4) * 8;
            bf16x8 af[4], bfr[4];
            #pragma unroll
            for (int mt = 0; mt < 4; ++mt)
                af[mt] = *(const bf16x8*)(&As[buf][(waveM + mt * 16 + (lane & 15)) * BK + kfrag]);
            #pragma unroll
            for (int nt = 0; nt < 4; ++nt)
                bfr[nt] = *(const bf16x8*)(&Bs[buf][(waveN + nt * 16 + (lane & 15)) * BK + kfrag]);
            #pragma unroll
            for (int mt = 0; mt < 4; ++mt)
                #pragma unroll
                for (int nt = 0; nt < 4; ++nt)
                    // SWAPPED operands: output mapping transposed (see header)
                    acc[mt][nt] = __builtin_amdgcn_mfma_f32_16x16x32_bf16(
                        bfr[nt], af[mt], acc[mt][nt], 0, 0, 0);
        }
    };

    // 2-phase pipeline: stage(k+1) issued before compute(k); one barrier/K-step.
    stage(0, 0);
    __syncthreads();
    #pragma unroll
    for (int kt = 1; kt < NKT; ++kt) {
        stage(kt & 1, kt * BK);            // prefetch next tile (in flight during MFMA)
        compute((kt - 1) & 1);
        __syncthreads();                   // drain prefetch + barrier
    }

    // epilogue operand prefetch: latency hides under the final compute
    const int r0 = rowBase + waveM + (lane & 15);
    const int c0 = colBase + waveN + ((lane >> 4) << 2);
    const float beta = *beta_p;
    float xv[4];
    f32x4 y4[4];
    #pragma unroll
    for (int mt = 0; mt < 4; ++mt) xv[mt] = x2[r0 + mt * 16];
    #pragma unroll
    for (int nt = 0; nt < 4; ++nt) y4[nt] = *(const f32x4*)(y2 + c0 + nt * 16);

    compute((NKT - 1) & 1);
    __syncthreads();   // all waves done reading As/Bs before Cs overwrites them

    // ---- phase 1: compute z, write to swizzled LDS C-tile ----
    // in-tile row = waveM + mt*16 + (lane&15); 16B col-slot = waveN/4 + nt*4 + (lane>>4)
    #pragma unroll
    for (int mt = 0; mt < 4; ++mt) {
        const int trow = waveM + mt * 16 + (lane & 15);
        #pragma unroll
        for (int nt = 0; nt < 4; ++nt) {
            const f32x4 a = acc[mt][nt];
            f32x4 z;
            #pragma unroll
            for (int r = 0; r < 4; ++r) {
                float d2 = xv[mt] + y4[nt][r] - 2.0f * a[r];
                z[r] = beta - __builtin_amdgcn_sqrtf(fmaxf(d2, 0.0f));
            }
            const int slot = ((waveN >> 2) + nt * 4 + (lane >> 4)) ^ (trow & 7);
            *(f32x4*)(&Cs[trow * 128 + slot * 4]) = z;   // <=2-way bank conflict
        }
    }
    __syncthreads();

    // ---- phase 2: linear full-line stores; 2 rows x 512 B per instruction ----
    // wave owns 32 rows; lane L: row = wbase + i*2 + (L>>5), 16B chunk g = L&31
    {
        const int l5 = lane >> 5;
        const int g  = lane & 31;
        #pragma unroll
        for (int i = 0; i < 16; ++i) {
            const int trow = wid * 32 + i * 2 + l5;
            const int slot = g ^ (trow & 7);             // un-swizzle
            const f32x4 v = *(const f32x4*)(&Cs[trow * 128 + slot * 4]);
            *(f32x4*)(out + (size_t)(rowBase + trow) * NCOL + colBase + g * 4) = v;
        }
    }
}

extern "C" void kernel_launch(void* const* d_in, const int* in_sizes, int n_in,
                              void* d_out, int out_size, void* d_ws, size_t ws_size,
                              hipStream_t stream) {
    const float* X    = (const float*)d_in[0];   // 8192 x 256
    const float* Y    = (const float*)d_in[1];   // 256 x 8192
    const float* beta = (const float*)d_in[2];   // scalar
    float* out = (float*)d_out;

    // workspace layout
    char* ws = (char*)d_ws;
    unsigned short* Xb  = (unsigned short*)(ws);                           // 4 MB
    unsigned short* Ybt = (unsigned short*)(ws + (size_t)4 * 1024 * 1024); // 4 MB
    float* x2 = (float*)(ws + (size_t)8 * 1024 * 1024);                    // 32 KB
    float* y2 = (float*)(ws + (size_t)8 * 1024 * 1024 + 32 * 1024);        // 32 KB

    prep_x<<<NROW / 4, 256, 0, stream>>>(X, Xb, x2);
    prep_y<<<NCOL / 64, 256, 0, stream>>>(Y, Ybt, y2);

    dim3 grid(NROW / BM, NCOL / BN);
    l2_gemm<<<grid, 256, 0, stream>>>(Xb, Ybt, x2, y2, beta, out);
}